// Round 2
// baseline (1178.577 us; speedup 1.0000x reference)
//
#include <hip/hip_runtime.h>

#define SEQ 16
#define CH  512
#define NH  8
#define HD  64

typedef unsigned short u16;
typedef __attribute__((ext_vector_type(8))) short s8v;   // 8 x bf16 (4 VGPRs)
typedef __attribute__((ext_vector_type(4))) float f4v;   // 4 x f32 acc

__device__ __forceinline__ float bf2f(u16 u) {
    union { unsigned u; float f; } c; c.u = ((unsigned)u) << 16; return c.f;
}
__device__ __forceinline__ u16 f2bf(float f) {
    union { float f; unsigned u; } c; c.f = f;
    unsigned r = (c.u + 0x7FFFu + ((c.u >> 16) & 1u)) >> 16;
    return (u16)r;
}
__device__ __forceinline__ f4v mfma16(s8v a, s8v b, f4v c) {
    return __builtin_amdgcn_mfma_f32_16x16x32_bf16(a, b, c, 0, 0, 0);
}

// pool pair tables: p1 rows (8) then p2 rows (4)
__constant__ int POOL_A[12] = {2,5,1,0,8,14,11,10, 0,2,5,4};
__constant__ int POOL_B[12] = {3,6,4,7,9,15,12,13, 1,3,6,7};

// dst[Cc][R] = bf16(src[R][Cc]); src f32. 32x32 tiles, 256 threads
__global__ void transpose_f32_to_bf16(const float* __restrict__ src,
                                      u16* __restrict__ dst, int R, int Cc) {
    __shared__ u16 tile[32][34];
    int tx = threadIdx.x & 31, ty = threadIdx.x >> 5;
    int bx = blockIdx.x % (Cc >> 5), by = blockIdx.x / (Cc >> 5);
    int c0 = bx * 32, r0 = by * 32;
#pragma unroll
    for (int i = 0; i < 32; i += 8)
        tile[ty + i][tx] = f2bf(src[(size_t)(r0 + ty + i) * Cc + c0 + tx]);
    __syncthreads();
#pragma unroll
    for (int i = 0; i < 32; i += 8)
        dst[(size_t)(c0 + ty + i) * R + r0 + tx] = tile[tx][ty + i];
}

// LDS arena (bytes):
//   RA  @ 0      : 40960  = xs[16][520] (P1-P3) -> ks[32][520] (P4-P5) -> vT[512][40] (P6-P7)
//   RB  @ 40960  : 16640  = qs[16][520] (P3-P5) -> os[16][520] (P7-P8)
//   PS  @ 57600  : 33280  = pools_ln[32][520]   (P2-P6)
//   PB  @ 90880  : 10240  = P[8 waves][16][40]  (P5-P7)
// total 101120 B -> 1 block/CU (8 waves = 2/SIMD)
__global__ __launch_bounds__(512, 2) void fused_spa(
    const float* __restrict__ x,
    const u16*  __restrict__ WqT,
    const u16*  __restrict__ WkvT,
    const u16*  __restrict__ WpT,
    const float* __restrict__ bproj,
    const float* __restrict__ gamma,
    const float* __restrict__ beta,
    float* __restrict__ out)
{
    __shared__ __align__(16) unsigned char smem[101120];
    u16* RA = (u16*)smem;
    u16* RB = (u16*)(smem + 40960);
    u16* PS = (u16*)(smem + 57600);
    u16* PB = (u16*)(smem + 90880);

    const int tid  = (int)threadIdx.x;
    const int w    = tid >> 6;      // wave 0..7
    const int lane = tid & 63;
    const int l15  = lane & 15;
    const int quad = lane >> 4;
    const int b    = (int)blockIdx.x;
    const float* xg = x + (size_t)b * (SEQ * CH);

    // ---- P1: stage x (f32) -> xs[16][520] (bf16)
    {
        int row = tid >> 5, col = (tid & 31) << 4;   // 16 floats per thread
        const float4* s = (const float4*)(xg + row * CH + col);
        float4 f0 = s[0], f1 = s[1], f2 = s[2], f3 = s[3];
        s8v o0, o1;
        o0[0] = (short)f2bf(f0.x); o0[1] = (short)f2bf(f0.y);
        o0[2] = (short)f2bf(f0.z); o0[3] = (short)f2bf(f0.w);
        o0[4] = (short)f2bf(f1.x); o0[5] = (short)f2bf(f1.y);
        o0[6] = (short)f2bf(f1.z); o0[7] = (short)f2bf(f1.w);
        o1[0] = (short)f2bf(f2.x); o1[1] = (short)f2bf(f2.y);
        o1[2] = (short)f2bf(f2.z); o1[3] = (short)f2bf(f2.w);
        o1[4] = (short)f2bf(f3.x); o1[5] = (short)f2bf(f3.y);
        o1[6] = (short)f2bf(f3.z); o1[7] = (short)f2bf(f3.w);
        s8v* d = (s8v*)(RA + row * 520 + col);
        d[0] = o0; d[1] = o1;
    }
    __syncthreads();

    // ---- P2: pools + LayerNorm -> PS (rows 0..27 LN'd, 28..31 zero)
    {
        int col = lane << 3;
        float g[8], be[8];
        {
            float4 g0 = *(const float4*)&gamma[col], g1 = *(const float4*)&gamma[col + 4];
            float4 b0 = *(const float4*)&beta[col],  b1 = *(const float4*)&beta[col + 4];
            g[0]=g0.x; g[1]=g0.y; g[2]=g0.z; g[3]=g0.w;
            g[4]=g1.x; g[5]=g1.y; g[6]=g1.z; g[7]=g1.w;
            be[0]=b0.x; be[1]=b0.y; be[2]=b0.z; be[3]=b0.w;
            be[4]=b1.x; be[5]=b1.y; be[6]=b1.z; be[7]=b1.w;
        }
#pragma unroll
        for (int it = 0; it < 4; ++it) {
            int row = w + (it << 3);            // wave-uniform
            if (row >= 28) {                    // pad rows -> zero
                s8v z = {0,0,0,0,0,0,0,0};
                *(s8v*)&PS[row * 520 + col] = z;
                continue;
            }
            float v[8];
            if (row < 16) {
                s8v t = *(const s8v*)&RA[row * 520 + col];
#pragma unroll
                for (int j = 0; j < 8; ++j) v[j] = bf2f((u16)t[j]);
            } else {
                int ra = POOL_A[row - 16], rb = POOL_B[row - 16];
                s8v ta = *(const s8v*)&RA[ra * 520 + col];
                s8v tb = *(const s8v*)&RA[rb * 520 + col];
#pragma unroll
                for (int j = 0; j < 8; ++j)
                    v[j] = 0.5f * (bf2f((u16)ta[j]) + bf2f((u16)tb[j]));
            }
            float s = 0.f, s2 = 0.f;
#pragma unroll
            for (int j = 0; j < 8; ++j) { s += v[j]; s2 += v[j] * v[j]; }
#pragma unroll
            for (int d = 1; d < 64; d <<= 1) {
                s  += __shfl_xor(s, d);
                s2 += __shfl_xor(s2, d);
            }
            float mu   = s * (1.f / 512.f);
            float var  = s2 * (1.f / 512.f) - mu * mu;
            float rstd = rsqrtf(var + 1e-5f);
            s8v o;
#pragma unroll
            for (int j = 0; j < 8; ++j)
                o[j] = (short)f2bf((v[j] - mu) * rstd * g[j] + be[j]);
            *(s8v*)&PS[row * 520 + col] = o;
        }
    }
    __syncthreads();

    // ---- P3: q = x @ Wq, scaled by 1/8 -> qs (RB). wave w: n-tiles w*4..w*4+3
    {
        f4v acc[4] = {};
        for (int kt = 0; kt < 16; ++kt) {
            s8v a = *(const s8v*)&RA[l15 * 520 + (kt << 5) + (quad << 3)];
#pragma unroll
            for (int t = 0; t < 4; ++t) {
                int n0 = ((w << 2) + t) << 4;
                s8v bb = *(const s8v*)&WqT[(n0 + l15) * CH + (kt << 5) + (quad << 3)];
                acc[t] = mfma16(a, bb, acc[t]);
            }
        }
#pragma unroll
        for (int t = 0; t < 4; ++t) {
            int n0 = ((w << 2) + t) << 4;
#pragma unroll
            for (int r = 0; r < 4; ++r)
                RB[((quad << 2) + r) * 520 + n0 + l15] = f2bf(acc[t][r] * 0.125f);
        }
    }
    __syncthreads();

    // ---- P4: k = pools_ln @ Wkv[:, :512] -> ks (RA). B-frag shared by both M-tiles.
    {
        f4v a0c[4] = {}, a1c[4] = {};
        for (int kt = 0; kt < 16; ++kt) {
            s8v a0 = *(const s8v*)&PS[l15 * 520 + (kt << 5) + (quad << 3)];
            s8v a1 = *(const s8v*)&PS[(16 + l15) * 520 + (kt << 5) + (quad << 3)];
#pragma unroll
            for (int t = 0; t < 4; ++t) {
                int n0 = ((w << 2) + t) << 4;
                s8v bb = *(const s8v*)&WkvT[(n0 + l15) * CH + (kt << 5) + (quad << 3)];
                a0c[t] = mfma16(a0, bb, a0c[t]);
                a1c[t] = mfma16(a1, bb, a1c[t]);
            }
        }
#pragma unroll
        for (int t = 0; t < 4; ++t) {
            int n0 = ((w << 2) + t) << 4;
#pragma unroll
            for (int r = 0; r < 4; ++r) {
                RA[((quad << 2) + r) * 520 + n0 + l15]        = f2bf(a0c[t][r]);
                RA[(16 + (quad << 2) + r) * 520 + n0 + l15]   = f2bf(a1c[t][r]);
            }
        }
    }
    __syncthreads();

    // ---- P5: S = q k^T (per head = per wave), softmax, P -> PB
    {
        int h = w;
        f4v s0 = {}, s1 = {};
#pragma unroll
        for (int kt = 0; kt < 2; ++kt) {
            int off = h * HD + (kt << 5) + (quad << 3);
            s8v a  = *(const s8v*)&RB[l15 * 520 + off];
            s8v b0 = *(const s8v*)&RA[l15 * 520 + off];
            s8v b1 = *(const s8v*)&RA[(16 + l15) * 520 + off];
            s0 = mfma16(a, b0, s0);
            s1 = mfma16(a, b1, s1);
        }
        bool valid1 = (l15 < 12);   // keys 16+l15 < 28
#pragma unroll
        for (int r = 0; r < 4; ++r) {
            float v0 = s0[r];
            float v1 = valid1 ? s1[r] : -1e30f;
            float mx = fmaxf(v0, v1);
#pragma unroll
            for (int d = 1; d < 16; d <<= 1) mx = fmaxf(mx, __shfl_xor(mx, d));
            float p0 = __expf(v0 - mx);
            float p1 = valid1 ? __expf(v1 - mx) : 0.f;
            float sm = p0 + p1;
#pragma unroll
            for (int d = 1; d < 16; d <<= 1) sm += __shfl_xor(sm, d);
            float inv = 1.f / sm;
            int row = (quad << 2) + r;
            PB[(w * 16 + row) * 40 + l15]      = f2bf(p0 * inv);
            PB[(w * 16 + row) * 40 + 16 + l15] = f2bf(p1 * inv);
        }
    }
    __syncthreads();

    // ---- P6: v = pools_ln @ Wkv[:, 512:] -> vT[512][40] (RA), stored transposed
    {
        f4v a0c[4] = {}, a1c[4] = {};
        for (int kt = 0; kt < 16; ++kt) {
            s8v a0 = *(const s8v*)&PS[l15 * 520 + (kt << 5) + (quad << 3)];
            s8v a1 = *(const s8v*)&PS[(16 + l15) * 520 + (kt << 5) + (quad << 3)];
#pragma unroll
            for (int t = 0; t < 4; ++t) {
                int n0 = 512 + (((w << 2) + t) << 4);
                s8v bb = *(const s8v*)&WkvT[(n0 + l15) * CH + (kt << 5) + (quad << 3)];
                a0c[t] = mfma16(a0, bb, a0c[t]);
                a1c[t] = mfma16(a1, bb, a1c[t]);
            }
        }
#pragma unroll
        for (int t = 0; t < 4; ++t) {
            int c0 = ((w << 2) + t) << 4;       // v column (head*64+d)
#pragma unroll
            for (int r = 0; r < 4; ++r) {
                RA[(c0 + l15) * 40 + (quad << 2) + r]      = f2bf(a0c[t][r]); // keys 0-15
                RA[(c0 + l15) * 40 + 16 + (quad << 2) + r] = f2bf(a1c[t][r]); // keys 16-31 (28..31 = 0)
            }
        }
    }
    __syncthreads();

    // ---- P7: O = P @ v (per head = per wave) -> os (RB)
    {
        int h = w;
        s8v a = *(const s8v*)&PB[(w * 16 + l15) * 40 + (quad << 3)];
        f4v o[4] = {};
#pragma unroll
        for (int nt = 0; nt < 4; ++nt) {
            s8v bb = *(const s8v*)&RA[(h * HD + (nt << 4) + l15) * 40 + (quad << 3)];
            o[nt] = mfma16(a, bb, o[nt]);
        }
#pragma unroll
        for (int nt = 0; nt < 4; ++nt)
#pragma unroll
            for (int r = 0; r < 4; ++r)
                RB[((quad << 2) + r) * 520 + h * HD + (nt << 4) + l15] = f2bf(o[nt][r]);
    }
    __syncthreads();

    // ---- P8: out = os @ Wproj + bproj  (f32 store)
    {
        f4v acc[4] = {};
        for (int kt = 0; kt < 16; ++kt) {
            s8v a = *(const s8v*)&RB[l15 * 520 + (kt << 5) + (quad << 3)];
#pragma unroll
            for (int t = 0; t < 4; ++t) {
                int n0 = ((w << 2) + t) << 4;
                s8v bb = *(const s8v*)&WpT[(n0 + l15) * CH + (kt << 5) + (quad << 3)];
                acc[t] = mfma16(a, bb, acc[t]);
            }
        }
        float* og = out + (size_t)b * (SEQ * CH);
#pragma unroll
        for (int t = 0; t < 4; ++t) {
            int n0 = ((w << 2) + t) << 4;
            float bias = bproj[n0 + l15];
#pragma unroll
            for (int r = 0; r < 4; ++r)
                og[((quad << 2) + r) * CH + n0 + l15] = acc[t][r] + bias;
        }
    }
}

extern "C" void kernel_launch(void* const* d_in, const int* in_sizes, int n_in,
                              void* d_out, int out_size, void* d_ws, size_t ws_size,
                              hipStream_t stream) {
    const float* x     = (const float*)d_in[0];
    const float* Wq    = (const float*)d_in[1];
    const float* Wkv   = (const float*)d_in[2];
    const float* Wproj = (const float*)d_in[3];
    const float* bproj = (const float*)d_in[4];
    const float* gamma = (const float*)d_in[5];
    const float* beta  = (const float*)d_in[6];
    float* out = (float*)d_out;

    // workspace: transposed bf16 weights (WT[n][k]) for contiguous MFMA B-fragments
    u16* WqT  = (u16*)d_ws;                 // [512][512]
    u16* WkvT = WqT + 512 * 512;            // [1024][512]
    u16* WpT  = WkvT + 1024 * 512;          // [512][512]   (total 2 MiB)

    transpose_f32_to_bf16<<<256, 256, 0, stream>>>(Wq,    WqT,  512, 512);
    transpose_f32_to_bf16<<<512, 256, 0, stream>>>(Wkv,   WkvT, 512, 1024);
    transpose_f32_to_bf16<<<256, 256, 0, stream>>>(Wproj, WpT,  512, 512);

    fused_spa<<<4096, 512, 0, stream>>>(x, WqT, WkvT, WpT, bproj, gamma, beta, out);
}

// Round 3
// 596.764 us; speedup vs baseline: 1.9749x; 1.9749x over previous
//
#include <hip/hip_runtime.h>

typedef unsigned short u16;
typedef __attribute__((ext_vector_type(8))) short s8v;   // 8 x bf16
typedef __attribute__((ext_vector_type(4))) float f4v;   // 4 x f32

#define NB 4   // batches per block

__device__ __forceinline__ float bf2f(u16 u) {
    union { unsigned u; float f; } c; c.u = ((unsigned)u) << 16; return c.f;
}
__device__ __forceinline__ u16 f2bf(float f) {
    union { float f; unsigned u; } c; c.f = f;
    return (u16)((c.u + 0x7FFFu + ((c.u >> 16) & 1u)) >> 16);
}
__device__ __forceinline__ f4v mfma16(s8v a, s8v b, f4v c) {
    return __builtin_amdgcn_mfma_f32_16x16x32_bf16(a, b, c, 0, 0, 0);
}

__constant__ int POOL_A[12] = {2,5,1,0,8,14,11,10, 0,2,5,4};
__constant__ int POOL_B[12] = {3,6,4,7,9,15,12,13, 1,3,6,7};

// ---- prep: pack Wcat = [Wq_h | diag(g)Wk_h | diag(g)Wv_h] per head, fragment-major.
// Wfrag[((h*12+nt)*16+kt)*512 + lane*8 + j] = B-frag element B[n=nt*16+l15][k=kt*32+quad*8+j]
__global__ void pack_wcat(const float* __restrict__ Wq, const float* __restrict__ Wkv,
                          const float* __restrict__ gamma, u16* __restrict__ Wfrag) {
    int blk = blockIdx.x;               // (h*12+nt)*16+kt, 1536 blocks
    int kt = blk & 15, hn = blk >> 4;
    int nt = hn % 12, h = hn / 12;
    int lane = threadIdx.x, l15 = lane & 15, quad = lane >> 4;
    int r0 = kt * 32 + quad * 8;
    s8v v;
    if (nt < 4) {
        int c = h * 64 + nt * 16 + l15;
#pragma unroll
        for (int j = 0; j < 8; ++j) v[j] = (short)f2bf(Wq[(size_t)(r0 + j) * 512 + c]);
    } else {
        int c = (nt < 8) ? (h * 64 + (nt - 4) * 16 + l15)
                         : (512 + h * 64 + (nt - 8) * 16 + l15);
#pragma unroll
        for (int j = 0; j < 8; ++j)
            v[j] = (short)f2bf(gamma[r0 + j] * Wkv[(size_t)(r0 + j) * 1024 + c]);
    }
    *(s8v*)&Wfrag[(size_t)blk * 512 + lane * 8] = v;
}

// Wpfrag[((h*2+kt)*32+n)*512 + lane*8 + j] = Wproj[h*64+kt*32+quad*8+j][n*16+l15]
__global__ void pack_wp(const float* __restrict__ Wproj, u16* __restrict__ Wpfrag) {
    int blk = blockIdx.x;               // 512 blocks
    int n = blk & 31, hk = blk >> 5;
    int kt = hk & 1, h = hk >> 1;
    int lane = threadIdx.x, l15 = lane & 15, quad = lane >> 4;
    int r0 = h * 64 + kt * 32 + quad * 8;
    int c = n * 16 + l15;
    s8v v;
#pragma unroll
    for (int j = 0; j < 8; ++j) v[j] = (short)f2bf(Wproj[(size_t)(r0 + j) * 512 + c]);
    *(s8v*)&Wpfrag[(size_t)blk * 512 + lane * 8] = v;
}

// gkv[h*256 + s*64 + c]: s=0: gamma@Wk_h ; s=1: beta@Wk_h ; s=2: gamma@Wv_h ; s=3: beta@Wv_h
__global__ void gemv_g(const float* __restrict__ Wkv, const float* __restrict__ gamma,
                       const float* __restrict__ beta, float* __restrict__ gkv) {
    int t = blockIdx.x * 256 + threadIdx.x;   // 0..2047
    int h = t >> 8, s = (t >> 6) & 3, c = t & 63;
    int col = (s < 2) ? (h * 64 + c) : (512 + h * 64 + c);
    const float* vec = (s & 1) ? beta : gamma;
    float acc = 0.f;
    for (int r = 0; r < 512; ++r) acc += vec[r] * Wkv[(size_t)r * 1024 + col];
    gkv[t] = acc;
}

// ---- fused kernel: 4 batches/block, 1024 threads (16 waves)
// LDS: XS[64][520]bf16 | YS[64][136]f32 | QH/os[64][72]bf16 | KH[128][72]bf16
//      | VT[4][64][40]bf16 | PB[4][16][40]bf16 | stats
__global__ __launch_bounds__(1024) void fused_spa(
    const float* __restrict__ x,
    const u16*  __restrict__ Wfrag,
    const u16*  __restrict__ Wpfrag,
    const float* __restrict__ gkv,
    const float* __restrict__ bproj,
    float* __restrict__ out)
{
    __shared__ __align__(16) unsigned char smem[156224];
    u16*   XS      = (u16*)smem;                  // [64][520]
    float* YS      = (float*)(smem + 66560);      // [64][136]
    u16*   QH      = (u16*)(smem + 101376);       // [64][72]
    u16*   KH      = (u16*)(smem + 110592);       // [128][72]
    u16*   VT      = (u16*)(smem + 129024);       // [4][64][40]
    u16*   PB      = (u16*)(smem + 149504);       // [4][16][40]
    float* STraw   = (float*)(smem + 154624);     // [64][2]  (mu, E[x^2])
    float* STcross = (float*)(smem + 155136);     // [48]
    float* STfin   = (float*)(smem + 155328);     // [112][2] (rstd, -rstd*mu)

    const int tid  = (int)threadIdx.x;
    const int w    = tid >> 6;
    const int lane = tid & 63;
    const int l15  = lane & 15;
    const int quad = lane >> 4;
    const int b0   = (int)blockIdx.x * NB;
    const size_t grow0 = (size_t)b0 * 16;         // global row base

    // P1: stage x (f32) -> XS bf16. thread: row=tid>>4 (0..63), 32 cols
    {
        int row = tid >> 4, col = (tid & 15) * 32;
        const float4* src = (const float4*)(x + (grow0 + row) * 512 + col);
        u16* dst = XS + row * 520 + col;
#pragma unroll
        for (int i = 0; i < 4; ++i) {
            float4 f0 = src[2 * i], f1 = src[2 * i + 1];
            s8v o;
            o[0] = (short)f2bf(f0.x); o[1] = (short)f2bf(f0.y);
            o[2] = (short)f2bf(f0.z); o[3] = (short)f2bf(f0.w);
            o[4] = (short)f2bf(f1.x); o[5] = (short)f2bf(f1.y);
            o[6] = (short)f2bf(f1.z); o[7] = (short)f2bf(f1.w);
            *(s8v*)(dst + i * 8) = o;
        }
    }
    __syncthreads();

    // P2a: per-row stats + cross dots
    {
#pragma unroll
        for (int i = 0; i < 4; ++i) {
            int row = w * 4 + i;                  // 0..63
            s8v t = *(const s8v*)&XS[row * 520 + lane * 8];
            float s = 0.f, s2 = 0.f;
#pragma unroll
            for (int j = 0; j < 8; ++j) { float v = bf2f((u16)t[j]); s += v; s2 += v * v; }
#pragma unroll
            for (int d = 1; d < 64; d <<= 1) { s += __shfl_xor(s, d); s2 += __shfl_xor(s2, d); }
            if (lane == 0) { STraw[row * 2] = s * (1.f/512.f); STraw[row * 2 + 1] = s2 * (1.f/512.f); }
        }
#pragma unroll
        for (int i = 0; i < 3; ++i) {
            int d = w * 3 + i;                    // 0..47
            int batch = d / 12, pr = d % 12;
            int ra = batch * 16 + POOL_A[pr], rb = batch * 16 + POOL_B[pr];
            s8v ta = *(const s8v*)&XS[ra * 520 + lane * 8];
            s8v tb = *(const s8v*)&XS[rb * 520 + lane * 8];
            float s = 0.f;
#pragma unroll
            for (int j = 0; j < 8; ++j) s += bf2f((u16)ta[j]) * bf2f((u16)tb[j]);
#pragma unroll
            for (int dd = 1; dd < 64; dd <<= 1) s += __shfl_xor(s, dd);
            if (lane == 0) STcross[batch * 12 + pr] = s * (1.f/512.f);
        }
    }
    __syncthreads();

    // P2b: finalize (rstd, -rstd*mu) for 4*28 pool rows
    if (tid < 112) {
        int batch = tid / 28, pr = tid % 28;
        float mu, E2;
        if (pr < 16) {
            mu = STraw[(batch * 16 + pr) * 2];
            E2 = STraw[(batch * 16 + pr) * 2 + 1];
        } else {
            int j = pr - 16;
            int ra = batch * 16 + POOL_A[j], rb = batch * 16 + POOL_B[j];
            float ma = STraw[ra * 2], mb = STraw[rb * 2];
            float Ea = STraw[ra * 2 + 1], Eb = STraw[rb * 2 + 1];
            mu = 0.5f * (ma + mb);
            E2 = 0.25f * (Ea + 2.f * STcross[batch * 12 + j] + Eb);
        }
        float var = E2 - mu * mu;
        float rstd = rsqrtf(var + 1e-5f);
        STfin[tid * 2] = rstd;
        STfin[tid * 2 + 1] = -rstd * mu;
    }
    __syncthreads();

    f4v psum[8] = {};   // proj accumulators: tiles (m 0..3) x (n = w*2, w*2+1)

    for (int h = 0; h < 8; ++h) {
        // P3a: [q|k|v] GEMM for this head. waves 0..11: n-tile = w, 4 M-tiles each.
        if (w < 12) {
            f4v acc[4] = {};
            const u16* bp = Wfrag + ((size_t)(h * 12 + w) * 16) * 512 + lane * 8;
            for (int kt = 0; kt < 16; ++kt) {
                s8v bb = *(const s8v*)(bp + kt * 512);
                int ka = kt * 32 + quad * 8;
#pragma unroll
                for (int m = 0; m < 4; ++m) {
                    s8v a = *(const s8v*)&XS[(m * 16 + l15) * 520 + ka];
                    acc[m] = mfma16(a, bb, acc[m]);
                }
            }
            if (w < 4) {            // q (scaled by 1/8)
#pragma unroll
                for (int m = 0; m < 4; ++m)
#pragma unroll
                    for (int r = 0; r < 4; ++r)
                        QH[(m * 16 + quad * 4 + r) * 72 + w * 16 + l15] = f2bf(acc[m][r] * 0.125f);
            } else if (w < 8) {     // raw Yk (f32)
#pragma unroll
                for (int m = 0; m < 4; ++m)
#pragma unroll
                    for (int r = 0; r < 4; ++r)
                        YS[(m * 16 + quad * 4 + r) * 136 + (w - 4) * 16 + l15] = acc[m][r];
            } else {                // raw Yv (f32)
#pragma unroll
                for (int m = 0; m < 4; ++m)
#pragma unroll
                    for (int r = 0; r < 4; ++r)
                        YS[(m * 16 + quad * 4 + r) * 136 + 64 + (w - 8) * 16 + l15] = acc[m][r];
            }
        }
        __syncthreads();

        // P3b: form k (KH) and v-transposed (VT) from raw Y via per-row affine
        {
            int rowid = tid >> 3;             // 0..127
            int c0 = (tid & 7) * 8;           // 0..56
            int batch = rowid >> 5, pr = rowid & 31;
            if (pr < 28) {
                float alpha = STfin[(batch * 28 + pr) * 2];
                float beta_ = STfin[(batch * 28 + pr) * 2 + 1];
                float yk[8], yv[8];
                if (pr < 16) {
                    const float* yr = YS + (batch * 16 + pr) * 136;
#pragma unroll
                    for (int i = 0; i < 8; ++i) { yk[i] = yr[c0 + i]; yv[i] = yr[64 + c0 + i]; }
                } else {
                    int j = pr - 16;
                    const float* ya = YS + (batch * 16 + POOL_A[j]) * 136;
                    const float* yb = YS + (batch * 16 + POOL_B[j]) * 136;
#pragma unroll
                    for (int i = 0; i < 8; ++i) {
                        yk[i] = 0.5f * (ya[c0 + i] + yb[c0 + i]);
                        yv[i] = 0.5f * (ya[64 + c0 + i] + yb[64 + c0 + i]);
                    }
                }
                const float* g = gkv + h * 256;
                s8v kk;
#pragma unroll
                for (int i = 0; i < 8; ++i) {
                    float kf = alpha * yk[i] + beta_ * g[c0 + i]       + g[64 + c0 + i];
                    float vf = alpha * yv[i] + beta_ * g[128 + c0 + i] + g[192 + c0 + i];
                    kk[i] = (short)f2bf(kf);
                    VT[(batch * 64 + c0 + i) * 40 + pr] = f2bf(vf);
                }
                *(s8v*)&KH[(batch * 32 + pr) * 72 + c0] = kk;
            } else {
                s8v z = {0,0,0,0,0,0,0,0};
                *(s8v*)&KH[(batch * 32 + pr) * 72 + c0] = z;
#pragma unroll
                for (int i = 0; i < 8; ++i) VT[(batch * 64 + c0 + i) * 40 + pr] = 0;
            }
        }
        __syncthreads();

        // P3cd: attention for this head. waves 0..3, batch = w.
        if (w < 4) {
            int batch = w;
            f4v s0 = {}, s1 = {};
#pragma unroll
            for (int kt = 0; kt < 2; ++kt) {
                int ka = kt * 32 + quad * 8;
                s8v aq  = *(const s8v*)&QH[(batch * 16 + l15) * 72 + ka];
                s8v bk0 = *(const s8v*)&KH[(batch * 32 + l15) * 72 + ka];
                s8v bk1 = *(const s8v*)&KH[(batch * 32 + 16 + l15) * 72 + ka];
                s0 = mfma16(aq, bk0, s0);
                s1 = mfma16(aq, bk1, s1);
            }
            bool valid1 = (l15 < 12);
#pragma unroll
            for (int r = 0; r < 4; ++r) {
                float v0 = s0[r];
                float v1 = valid1 ? s1[r] : -1e30f;
                float mx = fmaxf(v0, v1);
#pragma unroll
                for (int d = 1; d < 16; d <<= 1) mx = fmaxf(mx, __shfl_xor(mx, d));
                float p0 = __expf(v0 - mx);
                float p1 = valid1 ? __expf(v1 - mx) : 0.f;
                float sm = p0 + p1;
#pragma unroll
                for (int d = 1; d < 16; d <<= 1) sm += __shfl_xor(sm, d);
                float inv = 1.f / sm;
                int row = quad * 4 + r;
                PB[(batch * 16 + row) * 40 + l15]      = f2bf(p0 * inv);
                PB[(batch * 16 + row) * 40 + 16 + l15] = f2bf(p1 * inv);
            }
            // PV (same wave reads its own P writes; compiler inserts lgkm waits)
            s8v ap = *(const s8v*)&PB[(batch * 16 + l15) * 40 + quad * 8];
#pragma unroll
            for (int nt = 0; nt < 4; ++nt) {
                s8v bv = *(const s8v*)&VT[(batch * 64 + nt * 16 + l15) * 40 + quad * 8];
                f4v o = {};
                o = mfma16(ap, bv, o);
#pragma unroll
                for (int r = 0; r < 4; ++r)
                    QH[(batch * 16 + quad * 4 + r) * 72 + nt * 16 + l15] = f2bf(o[r]);  // os overlay
            }
        }
        __syncthreads();

        // P3e: proj accumulation, all 16 waves. out_cols n = w*2 + {0,1}, K-slice = this head.
        {
#pragma unroll
            for (int kt = 0; kt < 2; ++kt) {
                int ka = kt * 32 + quad * 8;
                s8v a[4];
#pragma unroll
                for (int m = 0; m < 4; ++m)
                    a[m] = *(const s8v*)&QH[(m * 16 + l15) * 72 + ka];
#pragma unroll
                for (int nn = 0; nn < 2; ++nn) {
                    int n = w * 2 + nn;
                    s8v bb = *(const s8v*)&Wpfrag[((size_t)((h * 2 + kt) * 32 + n)) * 512 + lane * 8];
#pragma unroll
                    for (int m = 0; m < 4; ++m)
                        psum[m * 2 + nn] = mfma16(a[m], bb, psum[m * 2 + nn]);
                }
            }
        }
        __syncthreads();
    }

    // P4: write out (f32) + bias
#pragma unroll
    for (int nn = 0; nn < 2; ++nn) {
        int n = w * 2 + nn;
        float bias = bproj[n * 16 + l15];
#pragma unroll
        for (int m = 0; m < 4; ++m)
#pragma unroll
            for (int r = 0; r < 4; ++r)
                out[(grow0 + m * 16 + quad * 4 + r) * 512 + n * 16 + l15] =
                    psum[m * 2 + nn][r] + bias;
    }
}

extern "C" void kernel_launch(void* const* d_in, const int* in_sizes, int n_in,
                              void* d_out, int out_size, void* d_ws, size_t ws_size,
                              hipStream_t stream) {
    const float* x     = (const float*)d_in[0];
    const float* Wq    = (const float*)d_in[1];
    const float* Wkv   = (const float*)d_in[2];
    const float* Wproj = (const float*)d_in[3];
    const float* bproj = (const float*)d_in[4];
    const float* gamma = (const float*)d_in[5];
    const float* beta  = (const float*)d_in[6];
    float* out = (float*)d_out;

    u16*   Wfrag  = (u16*)d_ws;                      // 1536*512 halves = 1.5 MiB
    u16*   Wpfrag = Wfrag + (size_t)1536 * 512;      // 512*512 halves = 0.5 MiB
    float* gkv    = (float*)(Wpfrag + (size_t)512 * 512);  // 2048 f32 = 8 KiB

    pack_wcat<<<1536, 64, 0, stream>>>(Wq, Wkv, gamma, Wfrag);
    pack_wp<<<512, 64, 0, stream>>>(Wproj, Wpfrag);
    gemv_g<<<8, 256, 0, stream>>>(Wkv, gamma, beta, gkv);

    fused_spa<<<4096 / NB, 1024, 0, stream>>>(x, Wfrag, Wpfrag, gkv, bproj, out);
}